// Round 12
// baseline (18.997 us; speedup 1.0000x reference)
//
#include <hip/hip_runtime.h>

// Batched 4x4 symmetric eigenvalues via CLOSED-FORM quartic (R9/R11 math).
// R12: FOUR matrices per thread. Identical per-matrix math; the experiment
// isolates the memory system: 10x16B independent loads + 4x16B stores per
// thread (was 5x8B loads + 1x16B store per matrix), wave count 16K -> 4K,
// whole grid resident (1024 blocks = 4/CU = 4 waves/SIMD at lb(256,4)),
// 4 independent dependency chains per thread.
// Round-fit model: T = 20ns*slots + 10.3us const. R8 ruled out per-wave
// cost; this round tests memory-MLP vs fixed-overhead for the const.
//
// H diag = concat(E1,E2); strict upper = C in row-major pair order
// (0,1),(0,2),(0,3),(1,2),(1,3),(2,3).

__device__ __forceinline__ float4 eig1(
    float h0, float h1, float h2, float h3,
    float o01, float o02, float o03, float o12, float o13, float o23)
{
    // Shift to traceless: B = H - m I.
    float m = (h0 + h1 + h2 + h3) * 0.25f;
    float b0 = h0 - m, b1 = h1 - m, b2 = h2 - m, b3 = h3 - m;

    // Invariants. p = -tr(B^2)/2.
    float q01 = o01 * o01, q02 = o02 * o02, q03 = o03 * o03;
    float q12 = o12 * o12, q13 = o13 * o13, q23 = o23 * o23;
    float soff = q01 + q02 + q03 + q12 + q13 + q23;
    float b0s = b0 * b0, b1s = b1 * b1, b2s = b2 * b2, b3s = b3 * b3;
    float tr2 = b0s + b1s + b2s + b3s + 2.0f * soff;
    float p = -0.5f * tr2;

    // q = -tr(B^3)/3.
    float cub = b0s * b0 + b1s * b1 + b2s * b2 + b3s * b3;
    float mix = (b0 + b1) * q01 + (b0 + b2) * q02 + (b0 + b3) * q03
              + (b1 + b2) * q12 + (b1 + b3) * q13 + (b2 + b3) * q23;
    float tri = o01 * o02 * o12 + o01 * o03 * o13
              + o02 * o03 * o23 + o12 * o13 * o23;
    float tr3 = cub + 3.0f * mix + 6.0f * tri;
    float q = -tr3 * (1.0f / 3.0f);

    // r = det(B), cofactor expansion with CSE (R9-verified).
    float A1 = fmaf(b2, b3, -q23);
    float A2 = fmaf(o12, b3, -(o23 * o13));
    float A3 = fmaf(-b2, o13, o12 * o23);
    float A4 = fmaf(o02, b3, -(o23 * o03));
    float A5 = fmaf(-b2, o03, o02 * o23);
    float A6 = fmaf(o02, o13, -(o12 * o03));
    float M00 = b1 * A1 - o12 * A2 + o13 * A3;
    float M01 = o01 * A1 - o12 * A4 + o13 * A5;
    float M02 = o01 * A2 - b1 * A4 + o13 * A6;
    float M03 = o01 * A3 - b1 * A5 + o12 * A6;
    float r = b0 * M00 - o01 * M01 + o02 * M02 - o03 * M03;

    // Depressed resolvent cubic: w^3 + P w + Q. All roots real.
    float pp = p * p;
    float P = fmaf(pp, -(1.0f / 3.0f), -4.0f * r);
    float Q = fmaf(p, fmaf(pp, -(2.0f / 27.0f), (8.0f / 3.0f) * r), -(q * q));
    float R2 = fmaxf(P * (-1.0f / 3.0f), 0.0f);
    float R = __builtin_amdgcn_sqrtf(R2);
    float R3 = R2 * R;
    float t = -Q * __builtin_amdgcn_rcpf(fmaf(2.0f, R3, 1e-30f));
    t = fminf(fmaxf(t, -1.0f), 1.0f);

    // acos via Hastings A&S 4.4.46 (R11-proven), branchless reflection.
    float x = fabsf(t);
    float sq = __builtin_amdgcn_sqrtf(fmaxf(1.0f - x, 0.0f));
    float pol = fmaf(x, -0.0012624911f, 0.0066700901f);
    pol = fmaf(x, pol, -0.0170881256f);
    pol = fmaf(x, pol, 0.0308918810f);
    pol = fmaf(x, pol, -0.0501743046f);
    pol = fmaf(x, pol, 0.0889789874f);
    pol = fmaf(x, pol, -0.2145988016f);
    pol = fmaf(x, pol, 1.5707963050f);
    float ap = sq * pol;
    float ac = (t >= 0.0f) ? ap : (3.14159265f - ap);

    // HW trig in revolutions: phi_rev = ac/(6 pi) in [0, 1/6].
    float phi_rev = ac * 0.05305164769f;
    float cph = __builtin_amdgcn_cosf(phi_rev);
    float sph = __builtin_amdgcn_sinf(phi_rev);

    float Rc = R * cph;
    float Rs = R * sph * 1.7320508f;
    float u0 = p * (-2.0f / 3.0f);
    float z1 = fmaf(2.0f, Rc, u0);
    float z2 = u0 - Rc - Rs;
    float z3 = u0 - Rc + Rs;
    float s1 = __builtin_amdgcn_sqrtf(fmaxf(z1, 0.0f));
    float s2 = __builtin_amdgcn_sqrtf(fmaxf(z2, 0.0f));
    float s3 = __builtin_amdgcn_sqrtf(fmaxf(z3, 0.0f));

    float hh = copysignf(0.5f, -q);
    float w = fmaf(hh, s1 + s2 + s3, m);
    float xx = fmaf(hh, s1 - s2 - s3, m);
    float y = fmaf(hh, s2 - s1 - s3, m);
    float z = fmaf(hh, s3 - s1 - s2, m);

#define CSWAP(u, v) { float lo = fminf(u, v), hi = fmaxf(u, v); u = lo; v = hi; }
    CSWAP(w, xx); CSWAP(y, z); CSWAP(w, y); CSWAP(xx, z); CSWAP(xx, y);
#undef CSWAP
    return make_float4(w, xx, y, z);
}

__global__ __launch_bounds__(256, 4) void eig4_closed4_kernel(
    const float* __restrict__ E1,
    const float* __restrict__ E2,
    const float* __restrict__ C,
    float* __restrict__ out,
    int Bq)  // B/4 threads, 4 matrices each
{
    int t = blockIdx.x * blockDim.x + threadIdx.x;
    if (t >= Bq) return;

    // 10 independent 16B loads, all issued before use (max MLP).
    const float4* e1p = reinterpret_cast<const float4*>(E1 + 8 * t);
    const float4* e2p = reinterpret_cast<const float4*>(E2 + 8 * t);
    const float4* cp  = reinterpret_cast<const float4*>(C + 24 * t);
    float4 e1a = e1p[0], e1b = e1p[1];
    float4 e2a = e2p[0], e2b = e2p[1];
    float4 c0 = cp[0], c1 = cp[1], c2 = cp[2];
    float4 c3 = cp[3], c4 = cp[4], c5 = cp[5];

    // mat k strict-upper = C[24t+6k .. 24t+6k+5].
    float4 r0 = eig1(e1a.x, e1a.y, e2a.x, e2a.y,
                     c0.x, c0.y, c0.z, c0.w, c1.x, c1.y);
    float4 r1 = eig1(e1a.z, e1a.w, e2a.z, e2a.w,
                     c1.z, c1.w, c2.x, c2.y, c2.z, c2.w);
    float4 r2 = eig1(e1b.x, e1b.y, e2b.x, e2b.y,
                     c3.x, c3.y, c3.z, c3.w, c4.x, c4.y);
    float4 r3 = eig1(e1b.z, e1b.w, e2b.z, e2b.w,
                     c4.z, c4.w, c5.x, c5.y, c5.z, c5.w);

    float4* op = reinterpret_cast<float4*>(out + 16 * t);
    op[0] = r0;
    op[1] = r1;
    op[2] = r2;
    op[3] = r3;
}

extern "C" void kernel_launch(void* const* d_in, const int* in_sizes, int n_in,
                              void* d_out, int out_size, void* d_ws, size_t ws_size,
                              hipStream_t stream)
{
    const float* E1 = (const float*)d_in[0];
    const float* E2 = (const float*)d_in[1];
    const float* C  = (const float*)d_in[2];
    float* out = (float*)d_out;

    int B = in_sizes[0] / 2;   // E1 is [B, 2]
    int Bq = B / 4;            // B = 2^20, divisible by 4
    int block = 256;
    int grid = (Bq + block - 1) / block;
    eig4_closed4_kernel<<<grid, block, 0, stream>>>(E1, E2, C, out, Bq);
}

// Round 15
// 15.003 us; speedup vs baseline: 1.2663x; 1.2663x over previous
//
#include <hip/hip_runtime.h>

// Batched 4x4 symmetric eigenvalues via CLOSED-FORM quartic (R9/R11 math).
// R13/R15: TWO matrices per thread at FULL occupancy (lb(256,8)).
//   R12 taught: 4/thread at 4 waves/SIMD regressed (latency exposed) ->
//   occupancy >= 8 waves/SIMD is mandatory. This tests the untested middle:
//   2x in-flight bytes + 2 independent chains per thread, 8 waves/SIMD,
//   grid = 2048 blocks = 8 blocks/CU -> whole problem resident, no churn.
//   All 5 input float4 loads issued up-front (MLP), matrices computed
//   sequentially to cap register pressure under the 64-VGPR/8-wave budget.
// (R14 was a compile fix: sort temporaries renamed, they shadowed the
//  h0/h1 diagonal parameters.)
//
// H diag = concat(E1,E2); strict upper = C in row-major pair order
// (0,1),(0,2),(0,3),(1,2),(1,3),(2,3).

__device__ __forceinline__ float4 eig1(
    float h0, float h1, float h2, float h3,
    float o01, float o02, float o03, float o12, float o13, float o23)
{
    // Shift to traceless: B = H - m I.
    float m = (h0 + h1 + h2 + h3) * 0.25f;
    float b0 = h0 - m, b1 = h1 - m, b2 = h2 - m, b3 = h3 - m;

    // Invariants. p = -tr(B^2)/2.
    float q01 = o01 * o01, q02 = o02 * o02, q03 = o03 * o03;
    float q12 = o12 * o12, q13 = o13 * o13, q23 = o23 * o23;
    float soff = q01 + q02 + q03 + q12 + q13 + q23;
    float b0s = b0 * b0, b1s = b1 * b1, b2s = b2 * b2, b3s = b3 * b3;
    float tr2 = b0s + b1s + b2s + b3s + 2.0f * soff;
    float p = -0.5f * tr2;

    // q = -tr(B^3)/3.
    float cub = b0s * b0 + b1s * b1 + b2s * b2 + b3s * b3;
    float mix = (b0 + b1) * q01 + (b0 + b2) * q02 + (b0 + b3) * q03
              + (b1 + b2) * q12 + (b1 + b3) * q13 + (b2 + b3) * q23;
    float tri = o01 * o02 * o12 + o01 * o03 * o13
              + o02 * o03 * o23 + o12 * o13 * o23;
    float tr3 = cub + 3.0f * mix + 6.0f * tri;
    float q = -tr3 * (1.0f / 3.0f);

    // r = det(B), cofactor expansion with CSE (R9-verified).
    float A1 = fmaf(b2, b3, -q23);
    float A2 = fmaf(o12, b3, -(o23 * o13));
    float A3 = fmaf(-b2, o13, o12 * o23);
    float A4 = fmaf(o02, b3, -(o23 * o03));
    float A5 = fmaf(-b2, o03, o02 * o23);
    float A6 = fmaf(o02, o13, -(o12 * o03));
    float M00 = b1 * A1 - o12 * A2 + o13 * A3;
    float M01 = o01 * A1 - o12 * A4 + o13 * A5;
    float M02 = o01 * A2 - b1 * A4 + o13 * A6;
    float M03 = o01 * A3 - b1 * A5 + o12 * A6;
    float r = b0 * M00 - o01 * M01 + o02 * M02 - o03 * M03;

    // Depressed resolvent cubic: w^3 + P w + Q. All roots real.
    float pp = p * p;
    float P = fmaf(pp, -(1.0f / 3.0f), -4.0f * r);
    float Q = fmaf(p, fmaf(pp, -(2.0f / 27.0f), (8.0f / 3.0f) * r), -(q * q));
    float R2 = fmaxf(P * (-1.0f / 3.0f), 0.0f);
    float R = __builtin_amdgcn_sqrtf(R2);
    float R3 = R2 * R;
    float t = -Q * __builtin_amdgcn_rcpf(fmaf(2.0f, R3, 1e-30f));
    t = fminf(fmaxf(t, -1.0f), 1.0f);

    // acos via Hastings A&S 4.4.46 (R11-proven), branchless reflection.
    float x = fabsf(t);
    float sq = __builtin_amdgcn_sqrtf(fmaxf(1.0f - x, 0.0f));
    float pol = fmaf(x, -0.0012624911f, 0.0066700901f);
    pol = fmaf(x, pol, -0.0170881256f);
    pol = fmaf(x, pol, 0.0308918810f);
    pol = fmaf(x, pol, -0.0501743046f);
    pol = fmaf(x, pol, 0.0889789874f);
    pol = fmaf(x, pol, -0.2145988016f);
    pol = fmaf(x, pol, 1.5707963050f);
    float ap = sq * pol;
    float ac = (t >= 0.0f) ? ap : (3.14159265f - ap);

    // HW trig in revolutions: phi_rev = ac/(6 pi) in [0, 1/6].
    float phi_rev = ac * 0.05305164769f;
    float cph = __builtin_amdgcn_cosf(phi_rev);
    float sph = __builtin_amdgcn_sinf(phi_rev);

    float Rc = R * cph;
    float Rs = R * sph * 1.7320508f;
    float u0 = p * (-2.0f / 3.0f);
    float z1 = fmaf(2.0f, Rc, u0);
    float z2 = u0 - Rc - Rs;
    float z3 = u0 - Rc + Rs;
    float s1 = __builtin_amdgcn_sqrtf(fmaxf(z1, 0.0f));
    float s2 = __builtin_amdgcn_sqrtf(fmaxf(z2, 0.0f));
    float s3 = __builtin_amdgcn_sqrtf(fmaxf(z3, 0.0f));

    float hh = copysignf(0.5f, -q);
    float w = fmaf(hh, s1 + s2 + s3, m);
    float xx = fmaf(hh, s1 - s2 - s3, m);
    float y = fmaf(hh, s2 - s1 - s3, m);
    float z = fmaf(hh, s3 - s1 - s2, m);

    // Ascending sort via min/max tree (10 ops; fusable to v_min3/v_max3).
    float sl0 = fminf(w, xx), sh0 = fmaxf(w, xx);
    float sl1 = fminf(y, z),  sh1 = fmaxf(y, z);
    float mn = fminf(sl0, sl1);
    float mx = fmaxf(sh0, sh1);
    float a2 = fmaxf(sl0, sl1);
    float c2 = fminf(sh0, sh1);
    float mid1 = fminf(a2, c2);
    float mid2 = fmaxf(a2, c2);
    return make_float4(mn, mid1, mid2, mx);
}

__global__ __launch_bounds__(256, 8) void eig4_closed2_kernel(
    const float* __restrict__ E1,
    const float* __restrict__ E2,
    const float* __restrict__ C,
    float* __restrict__ out,
    int Bhalf)  // B/2 threads, 2 matrices each
{
    int t = blockIdx.x * blockDim.x + threadIdx.x;
    if (t >= Bhalf) return;

    // All 5 input loads issued up-front (independent, 16B, coalesced).
    float4 e1 = *reinterpret_cast<const float4*>(E1 + 4 * t);  // m0.E1, m1.E1
    float4 e2 = *reinterpret_cast<const float4*>(E2 + 4 * t);
    const float4* cp = reinterpret_cast<const float4*>(C + 12 * t);
    float4 c0 = cp[0];  // m0: c01 c02 c03 c12
    float4 c1 = cp[1];  // m0: c13 c23 | m1: c01 c02
    float4 c2 = cp[2];  // m1: c03 c12 c13 c23

    float4 r0 = eig1(e1.x, e1.y, e2.x, e2.y,
                     c0.x, c0.y, c0.z, c0.w, c1.x, c1.y);
    float4 r1 = eig1(e1.z, e1.w, e2.z, e2.w,
                     c1.z, c1.w, c2.x, c2.y, c2.z, c2.w);

    float4* op = reinterpret_cast<float4*>(out + 8 * t);
    op[0] = r0;
    op[1] = r1;
}

extern "C" void kernel_launch(void* const* d_in, const int* in_sizes, int n_in,
                              void* d_out, int out_size, void* d_ws, size_t ws_size,
                              hipStream_t stream)
{
    const float* E1 = (const float*)d_in[0];
    const float* E2 = (const float*)d_in[1];
    const float* C  = (const float*)d_in[2];
    float* out = (float*)d_out;

    int B = in_sizes[0] / 2;   // E1 is [B, 2]
    int Bhalf = B / 2;         // B = 2^20, even
    int block = 256;
    int grid = (Bhalf + block - 1) / block;  // 2048 blocks = 8/CU, resident
    eig4_closed2_kernel<<<grid, block, 0, stream>>>(E1, E2, C, out, Bhalf);
}